// Round 12
// baseline (613.374 us; speedup 1.0000x reference)
//
#include <hip/hip_runtime.h>
#include <hip/hip_bf16.h>

#define N_NODES 50000
#define N_EDGES 800000
#define N_BUCKETS 64
#define M_PAD 50048  // 391 * 128, pads GEMM A-inputs so staging never reads OOB
#define SCAN_NB 196  // ceil(50000 / 256)

typedef short short8 __attribute__((ext_vector_type(8)));
typedef float floatx4 __attribute__((ext_vector_type(4)));
typedef unsigned uint2v __attribute__((ext_vector_type(2)));

// ---- bf16 helpers (RNE) ---------------------------------------------------
__device__ __forceinline__ unsigned short f2bf(float f) {
    unsigned u = __float_as_uint(f);
    unsigned r = (u + 0x7fff + ((u >> 16) & 1)) >> 16;
    return (unsigned short)r;
}
__device__ __forceinline__ float bf2f(unsigned short h) {
    return __uint_as_float(((unsigned)h) << 16);
}
__device__ __forceinline__ void expand2(unsigned u, float& lo, float& hi) {
    lo = __uint_as_float(u << 16);
    hi = __uint_as_float(u & 0xffff0000u);
}
// 4 features from 8B (4 bf16)
__device__ __forceinline__ void accum4v(float* a, uint2v g, float w) {
    float lo, hi;
    expand2(g[0], lo, hi); a[0] += lo * w; a[1] += hi * w;
    expand2(g[1], lo, hi); a[2] += lo * w; a[3] += hi * w;
}
// 2 features from 4B (2 bf16)
__device__ __forceinline__ void accum2(float* a, unsigned g, float w) {
    float lo, hi;
    expand2(g, lo, hi); a[0] += lo * w; a[1] += hi * w;
}

// non-temporal gather loads: bypass L1 allocation (theory: L1 miss-path is
// the per-region ~70cyc serializer for random gathers)
__device__ __forceinline__ uint2v ntload8(const unsigned short* p) {
    return __builtin_nontemporal_load((const uint2v*)p);
}
__device__ __forceinline__ unsigned ntload4(const unsigned short* p) {
    return __builtin_nontemporal_load((const unsigned*)p);
}

// async global->LDS, 16B per lane; lds dest = wave-uniform base + lane*16
__device__ __forceinline__ void gload16(const void* gp, void* lp) {
    __builtin_amdgcn_global_load_lds(
        (const __attribute__((address_space(1))) unsigned int*)gp,
        (__attribute__((address_space(3))) unsigned int*)lp,
        16, 0, 0);
}

// ---------------------------------------------------------------------------
__global__ void k_init(int* __restrict__ cnt, float* __restrict__ gb) {
    int i = blockIdx.x * blockDim.x + threadIdx.x;
    if (i < N_NODES) cnt[i] = 0;
    if (i < N_BUCKETS * 256) gb[i] = 0.0f;
}

__global__ void k_count(const int* __restrict__ col, int* __restrict__ cnt) {
    int e = blockIdx.x * blockDim.x + threadIdx.x;
    if (e < N_EDGES) atomicAdd(&cnt[col[e]], 1);
}

// --- 3-phase hierarchical exclusive scan of cnt -> off/cursor --------------
__global__ __launch_bounds__(256) void k_scanA(const int* __restrict__ cnt,
                                               int* __restrict__ bsum) {
    __shared__ int red[256];
    int t = threadIdx.x;
    int i = blockIdx.x * 256 + t;
    red[t] = (i < N_NODES) ? cnt[i] : 0;
    __syncthreads();
    for (int d = 128; d > 0; d >>= 1) {
        if (t < d) red[t] += red[t + d];
        __syncthreads();
    }
    if (t == 0) bsum[blockIdx.x] = red[0];
}

__global__ __launch_bounds__(256) void k_scanB(const int* __restrict__ bsum,
                                               int* __restrict__ bbase,
                                               int* __restrict__ off) {
    __shared__ int sc[256];
    int t = threadIdx.x;
    sc[t] = (t < SCAN_NB) ? bsum[t] : 0;
    __syncthreads();
    for (int d = 1; d < 256; d <<= 1) {
        int v = 0;
        if (t >= d) v = sc[t - d];
        __syncthreads();
        if (t >= d) sc[t] += v;
        __syncthreads();
    }
    if (t < SCAN_NB) bbase[t] = sc[t] - bsum[t];  // exclusive
    if (t == 0) off[N_NODES] = N_EDGES;
}

__global__ __launch_bounds__(256) void k_scanC(const int* __restrict__ cnt,
                                               const int* __restrict__ bbase,
                                               int* __restrict__ off,
                                               int* __restrict__ cursor,
                                               float* __restrict__ dinv) {
    __shared__ int sc[256];
    int t = threadIdx.x;
    int i = blockIdx.x * 256 + t;
    int c = (i < N_NODES) ? cnt[i] : 0;
    sc[t] = c;
    __syncthreads();
    for (int d = 1; d < 256; d <<= 1) {
        int v = 0;
        if (t >= d) v = sc[t - d];
        __syncthreads();
        if (t >= d) sc[t] += v;
        __syncthreads();
    }
    if (i < N_NODES) {
        int excl = sc[t] - c + bbase[blockIdx.x];
        off[i] = excl;
        cursor[i] = excl;
        dinv[i] = 1.0f / sqrtf((float)(c + 1));
    }
}

__global__ void k_fill(const int* __restrict__ row, const int* __restrict__ col,
                       const float* __restrict__ dinv, int* __restrict__ cursor,
                       int2* __restrict__ epack) {
    int e = blockIdx.x * blockDim.x + threadIdx.x;
    if (e >= N_EDGES) return;
    int v = col[e];
    int p = atomicAdd(&cursor[v], 1);
    int r = row[e];
    epack[p] = make_int2(r, __float_as_int(dinv[r]));
}

// W [K][N] fp32 -> transposed split bf16 WT{h,l} [N][K] (weights stay exact)
__global__ void k_prepW(const float* __restrict__ W,
                        unsigned short* __restrict__ Th,
                        unsigned short* __restrict__ Tl, int K, int N) {
    int idx = blockIdx.x * blockDim.x + threadIdx.x;
    if (idx >= K * N) return;
    int n = idx / K, k = idx - n * K;
    float v = W[(size_t)k * N + n];
    unsigned short h = f2bf(v);
    Th[idx] = h;
    Tl[idx] = f2bf(v - bf2f(h));
}

// x fp32 -> bf16 (row-major)
__global__ void k_prepX(const float* __restrict__ x, unsigned short* __restrict__ xb) {
    int i = blockIdx.x * blockDim.x + threadIdx.x;
    if (i < N_NODES * 128) xb[i] = f2bf(x[i]);
}

// ---------------------------------------------------------------------------
// Wave-per-node aggregation with NON-TEMPORAL gathers:
//   res[v] = dinv[v] * ( x[v]*dinv[v] + sum_j x[r_j]*dinv[r_j] )
// One wave owns one node; each gather = ONE contiguous 512B/256B segment per
// wave-instruction, issued with the `nt` flag to bypass L1 allocation.
// POOL=0: row-major bf16 out. POOL=1: bias+relu+bucketed mean-pool.
template <int DIM, int POOL>
__global__ __launch_bounds__(256) void k_aggw(
    const unsigned short* __restrict__ xb, const int* __restrict__ off,
    const int2* __restrict__ epack, const float* __restrict__ dinv,
    const float* __restrict__ bias, unsigned short* __restrict__ outb,
    float* __restrict__ gb) {
    const int EPL = DIM / 64;     // features per lane: 4 (256) or 2 (128)
    __shared__ float gpart[256];
    if (POOL) {
        gpart[threadIdx.x] = 0.0f;
        __syncthreads();
    }
    int wv = threadIdx.x >> 6;        // wave within block
    int li = threadIdx.x & 63;        // lane
    int v = blockIdx.x * 4 + wv;      // node (grid divides N exactly)
    int f = li * EPL;
    float dv = dinv[v];
    const unsigned short* __restrict__ xf = xb + f;
    float a0[EPL], a1[EPL], a2[EPL], a3[EPL];
#pragma unroll
    for (int i = 0; i < EPL; ++i) { a0[i] = 0.f; a1[i] = 0.f; a2[i] = 0.f; a3[i] = 0.f; }
    if (EPL == 4) {
        uint2v sv = ntload8(&xf[(size_t)v * DIM]);
        accum4v(a0, sv, dv);
    } else {
        unsigned sv = ntload4(&xf[(size_t)v * DIM]);
        accum2(a0, sv, dv);
    }
    int s = off[v], e = off[v + 1];
    int j = s;
    for (; j + 4 <= e; j += 4) {
        int2 p0 = epack[j + 0];
        int2 p1 = epack[j + 1];
        int2 p2 = epack[j + 2];
        int2 p3 = epack[j + 3];
        if (EPL == 4) {
            uint2v g0 = ntload8(&xf[(size_t)p0.x * DIM]);
            uint2v g1 = ntload8(&xf[(size_t)p1.x * DIM]);
            uint2v g2 = ntload8(&xf[(size_t)p2.x * DIM]);
            uint2v g3 = ntload8(&xf[(size_t)p3.x * DIM]);
            accum4v(a0, g0, __int_as_float(p0.y));
            accum4v(a1, g1, __int_as_float(p1.y));
            accum4v(a2, g2, __int_as_float(p2.y));
            accum4v(a3, g3, __int_as_float(p3.y));
        } else {
            unsigned g0 = ntload4(&xf[(size_t)p0.x * DIM]);
            unsigned g1 = ntload4(&xf[(size_t)p1.x * DIM]);
            unsigned g2 = ntload4(&xf[(size_t)p2.x * DIM]);
            unsigned g3 = ntload4(&xf[(size_t)p3.x * DIM]);
            accum2(a0, g0, __int_as_float(p0.y));
            accum2(a1, g1, __int_as_float(p1.y));
            accum2(a2, g2, __int_as_float(p2.y));
            accum2(a3, g3, __int_as_float(p3.y));
        }
    }
    for (; j < e; ++j) {
        int2 p = epack[j];
        if (EPL == 4) {
            uint2v g = ntload8(&xf[(size_t)p.x * DIM]);
            accum4v(a0, g, __int_as_float(p.y));
        } else {
            unsigned g = ntload4(&xf[(size_t)p.x * DIM]);
            accum2(a0, g, __int_as_float(p.y));
        }
    }
    float acc[EPL];
#pragma unroll
    for (int i = 0; i < EPL; ++i)
        acc[i] = ((a0[i] + a1[i]) + (a2[i] + a3[i])) * dv;
    if (!POOL) {
        if (EPL == 4) {
            uint2 o;
            o.x = (unsigned)f2bf(acc[0]) | ((unsigned)f2bf(acc[1]) << 16);
            o.y = (unsigned)f2bf(acc[2]) | ((unsigned)f2bf(acc[3]) << 16);
            *(uint2*)&outb[(size_t)v * DIM + f] = o;
        } else {
            unsigned o = (unsigned)f2bf(acc[0]) | ((unsigned)f2bf(acc[1]) << 16);
            *(unsigned*)&outb[(size_t)v * DIM + f] = o;
        }
    } else {
#pragma unroll
        for (int i = 0; i < EPL; ++i) {
            float r = fmaxf(acc[i] + bias[f + i], 0.0f);
            atomicAdd(&gpart[f + i], r);
        }
        __syncthreads();
        atomicAdd(&gb[(blockIdx.x & (N_BUCKETS - 1)) * 256 + threadIdx.x],
                  gpart[threadIdx.x]);
    }
}

// ---------------------------------------------------------------------------
// bf16-A x split-bf16-B MFMA GEMM: C[M,N] = A[M,K] @ (Bh+Bl)[K,N] (+bias)(relu)
// B pre-transposed [N][K]. 128x128 tile, BK=32, double-buffered LDS.
// LDS k-chunks swizzled by (row>>1)&3 to break the 64B-row-stride conflicts.
template <int BIAS, int RELU>
__global__ __launch_bounds__(256) void k_gemm_b(
    const unsigned short* __restrict__ A,
    const unsigned short* __restrict__ Bh, const unsigned short* __restrict__ Bl,
    const float* __restrict__ bias, unsigned short* __restrict__ C,
    int M, int K, int N) {
    __shared__ unsigned short As[2][128 * 32];
    __shared__ unsigned short BsH[2][128 * 32];
    __shared__ unsigned short BsL[2][128 * 32];
    int tid = threadIdx.x;
    int lane = tid & 63;
    int w = tid >> 6;
    int wr = w & 1, wc = w >> 1;
    int bm = blockIdx.x * 128, bn = blockIdx.y * 128;

    floatx4 acc[4][4];
    floatx4 zero = {0.f, 0.f, 0.f, 0.f};
#pragma unroll
    for (int t = 0; t < 4; ++t)
#pragma unroll
        for (int u = 0; u < 4; ++u) acc[t][u] = zero;

    int c0 = w * 2, c1 = c0 + 1;
    int srow = lane >> 2;
    int kg = ((lane & 3) - ((lane >> 3) & 3)) & 3;  // global k-chunk (inverse swizzle)
    int kc = kg * 8;
    const unsigned short* Ap0 = A + (size_t)(bm + c0 * 16 + srow) * K + kc;
    const unsigned short* Ap1 = A + (size_t)(bm + c1 * 16 + srow) * K + kc;
    const unsigned short* Bh0 = Bh + (size_t)(bn + c0 * 16 + srow) * K + kc;
    const unsigned short* Bh1 = Bh + (size_t)(bn + c1 * 16 + srow) * K + kc;
    const unsigned short* Bl0 = Bl + (size_t)(bn + c0 * 16 + srow) * K + kc;
    const unsigned short* Bl1 = Bl + (size_t)(bn + c1 * 16 + srow) * K + kc;

    const int KT = K >> 5;
#define STAGE(half, k0)                                   \
    do {                                                  \
        gload16(Ap0 + (k0), &As[half][c0 * 512]);         \
        gload16(Ap1 + (k0), &As[half][c1 * 512]);         \
        gload16(Bh0 + (k0), &BsH[half][c0 * 512]);        \
        gload16(Bh1 + (k0), &BsH[half][c1 * 512]);        \
        gload16(Bl0 + (k0), &BsL[half][c0 * 512]);        \
        gload16(Bl1 + (k0), &BsL[half][c1 * 512]);        \
    } while (0)

    STAGE(0, 0);
    __syncthreads();

    int fr = lane & 15;            // m (A) / n (B) within 16-tile
    int fq = lane >> 4;            // k-chunk 0..3
    int cl = ((fq + (fr >> 1)) & 3) * 8;  // swizzled LDS k-chunk offset

    for (int kt = 0; kt < KT; ++kt) {
        int half = kt & 1;
        if (kt + 1 < KT) STAGE(1 - half, (kt + 1) * 32);
        short8 av[4], bhv[4], blv[4];
#pragma unroll
        for (int t = 0; t < 4; ++t) {
            av[t]  = *(const short8*)&As[half][(wr * 64 + t * 16 + fr) * 32 + cl];
            bhv[t] = *(const short8*)&BsH[half][(wc * 64 + t * 16 + fr) * 32 + cl];
            blv[t] = *(const short8*)&BsL[half][(wc * 64 + t * 16 + fr) * 32 + cl];
        }
#pragma unroll
        for (int t = 0; t < 4; ++t)
#pragma unroll
            for (int u = 0; u < 4; ++u) {
                acc[t][u] = __builtin_amdgcn_mfma_f32_16x16x32_bf16(av[t], bhv[u], acc[t][u], 0, 0, 0);
                acc[t][u] = __builtin_amdgcn_mfma_f32_16x16x32_bf16(av[t], blv[u], acc[t][u], 0, 0, 0);
            }
        __syncthreads();
    }
#undef STAGE

    // epilogue: C/D layout col = lane&15, row = (lane>>4)*4 + reg
#pragma unroll
    for (int u = 0; u < 4; ++u) {
        int colg = bn + wc * 64 + u * 16 + fr;
        float bv = BIAS ? bias[colg] : 0.0f;
#pragma unroll
        for (int t = 0; t < 4; ++t) {
#pragma unroll
            for (int r = 0; r < 4; ++r) {
                int rowg = bm + wr * 64 + t * 16 + fq * 4 + r;
                if (rowg < M) {
                    float o = acc[t][u][r] + bv;
                    if (RELU) o = fmaxf(o, 0.f);
                    C[(size_t)rowg * N + colg] = f2bf(o);
                }
            }
        }
    }
}

// tiny MLP; first reduces the 64 pool buckets
__global__ void k_mlp(const float* __restrict__ gb,
                      const float* __restrict__ Wf1, const float* __restrict__ bf1,
                      const float* __restrict__ Wf2, const float* __restrict__ bf2,
                      const float* __restrict__ Wf3, const float* __restrict__ bf3,
                      float* __restrict__ out) {
    __shared__ float s0[256], s1[128], s2[64];
    int t = threadIdx.x;
    float sum = 0.0f;
    for (int b = 0; b < N_BUCKETS; ++b) sum += gb[b * 256 + t];
    s0[t] = sum * (1.0f / (float)N_NODES);
    __syncthreads();
    if (t < 128) {
        float a = bf1[t];
        for (int k = 0; k < 256; ++k) a += s0[k] * Wf1[k * 128 + t];
        s1[t] = fmaxf(a, 0.0f);
    }
    __syncthreads();
    if (t < 64) {
        float a = bf2[t];
        for (int k = 0; k < 128; ++k) a += s1[k] * Wf2[k * 64 + t];
        s2[t] = fmaxf(a, 0.0f);
    }
    __syncthreads();
    if (t == 0) {
        float a = bf3[0];
        for (int k = 0; k < 64; ++k) a += s2[k] * Wf3[k];
        out[0] = a;
    }
}

extern "C" void kernel_launch(void* const* d_in, const int* in_sizes, int n_in,
                              void* d_out, int out_size, void* d_ws, size_t ws_size,
                              hipStream_t stream) {
    const float* x  = (const float*)d_in[0];
    const int* ei   = (const int*)d_in[1];
    const float* W1 = (const float*)d_in[2];
    const float* b1 = (const float*)d_in[3];
    const float* W2 = (const float*)d_in[4];
    const float* b2 = (const float*)d_in[5];
    const float* W3 = (const float*)d_in[6];
    const float* b3 = (const float*)d_in[7];
    const float* Wf1 = (const float*)d_in[8];
    const float* bf1 = (const float*)d_in[9];
    const float* Wf2 = (const float*)d_in[10];
    const float* bf2 = (const float*)d_in[11];
    const float* Wf3 = (const float*)d_in[12];
    const float* bf3 = (const float*)d_in[13];
    float* out = (float*)d_out;

    char* p = (char*)d_ws;
    auto alloc = [&](size_t bytes) {
        void* r = (void*)p;
        p += (bytes + 255) & ~((size_t)255);
        return r;
    };
    int*   cnt    = (int*)  alloc(N_NODES * sizeof(int));
    int*   off    = (int*)  alloc((N_NODES + 1) * sizeof(int));
    int*   cursor = (int*)  alloc(N_NODES * sizeof(int));
    int*   bsum   = (int*)  alloc(SCAN_NB * sizeof(int));
    int*   bbase  = (int*)  alloc(SCAN_NB * sizeof(int));
    float* dinv   = (float*)alloc(N_NODES * sizeof(float));
    int2*  epack  = (int2*) alloc((size_t)N_EDGES * sizeof(int2));
    float* gb     = (float*)alloc(N_BUCKETS * 256 * sizeof(float));
    unsigned short* W1h = (unsigned short*)alloc(128 * 256 * 2);
    unsigned short* W1l = (unsigned short*)alloc(128 * 256 * 2);
    unsigned short* W2h = (unsigned short*)alloc(256 * 512 * 2);
    unsigned short* W2l = (unsigned short*)alloc(256 * 512 * 2);
    unsigned short* W3h = (unsigned short*)alloc(512 * 256 * 2);
    unsigned short* W3l = (unsigned short*)alloc(512 * 256 * 2);
    unsigned short* xb = (unsigned short*)alloc((size_t)N_NODES * 128 * 2);
    unsigned short* t0 = (unsigned short*)alloc((size_t)M_PAD * 128 * 2);
    unsigned short* h1 = (unsigned short*)alloc((size_t)N_NODES * 256 * 2);
    unsigned short* t1 = (unsigned short*)alloc((size_t)M_PAD * 256 * 2);
    unsigned short* h2 = (unsigned short*)alloc((size_t)M_PAD * 512 * 2);
    unsigned short* t2 = (unsigned short*)alloc((size_t)N_NODES * 256 * 2);

    const int* row = ei;
    const int* col = ei + N_EDGES;

    const int NB = (N_NODES + 255) / 256;  // 196
    const int EB = (N_EDGES + 255) / 256;

    // CSR build + norm (hierarchical scan)
    k_init<<<NB, 256, 0, stream>>>(cnt, gb);
    k_count<<<EB, 256, 0, stream>>>(col, cnt);
    k_scanA<<<SCAN_NB, 256, 0, stream>>>(cnt, bsum);
    k_scanB<<<1, 256, 0, stream>>>(bsum, bbase, off);
    k_scanC<<<SCAN_NB, 256, 0, stream>>>(cnt, bbase, off, cursor, dinv);
    k_fill<<<EB, 256, 0, stream>>>(row, col, dinv, cursor, epack);

    // weight prep (transpose + exact split) and x -> bf16
    k_prepW<<<(128 * 256 + 255) / 256, 256, 0, stream>>>(W1, W1h, W1l, 128, 256);
    k_prepW<<<(256 * 512 + 255) / 256, 256, 0, stream>>>(W2, W2h, W2l, 256, 512);
    k_prepW<<<(512 * 256 + 255) / 256, 256, 0, stream>>>(W3, W3h, W3l, 512, 256);
    k_prepX<<<(N_NODES * 128 + 255) / 256, 256, 0, stream>>>(x, xb);

    const int M = N_NODES;
    const int MB = (M + 127) / 128; // 391

    // conv1: t0 = agg(xb); h1 = relu(t0@W1 + b1)
    k_aggw<128, 0><<<N_NODES / 4, 256, 0, stream>>>(
        xb, off, epack, dinv, nullptr, t0, nullptr);
    {
        dim3 grid(MB, 256 / 128);
        k_gemm_b<1, 1><<<grid, 256, 0, stream>>>(t0, W1h, W1l, b1, h1, M, 128, 256);
    }
    // conv2: t1 = agg(h1); h2 = relu(t1@W2 + b2)
    k_aggw<256, 0><<<N_NODES / 4, 256, 0, stream>>>(
        h1, off, epack, dinv, nullptr, t1, nullptr);
    {
        dim3 grid(MB, 512 / 128);
        k_gemm_b<1, 1><<<grid, 256, 0, stream>>>(t1, W2h, W2l, b2, h2, M, 256, 512);
    }
    // conv3: t2 = h2@W3; fused agg + bias + relu + bucketed mean-pool
    {
        dim3 grid(MB, 256 / 128);
        k_gemm_b<0, 0><<<grid, 256, 0, stream>>>(h2, W3h, W3l, nullptr, t2, M, 512, 256);
    }
    k_aggw<256, 1><<<N_NODES / 4, 256, 0, stream>>>(
        t2, off, epack, dinv, b3, nullptr, gb);

    // MLP (reduces buckets internally)
    k_mlp<<<1, 256, 0, stream>>>(gb, Wf1, bf1, Wf2, bf2, Wf3, bf3, out);
}

// Round 13
// 505.675 us; speedup vs baseline: 1.2130x; 1.2130x over previous
//
#include <hip/hip_runtime.h>
#include <hip/hip_bf16.h>

#define N_NODES 50000
#define N_EDGES 800000
#define N_BUCKETS 64
#define M_PAD 50048  // 391 * 128, pads GEMM A-inputs so staging never reads OOB
#define SCAN_NB 196  // ceil(50000 / 256)

typedef short short8 __attribute__((ext_vector_type(8)));
typedef float floatx4 __attribute__((ext_vector_type(4)));

// ---- bf16 helpers (RNE) ---------------------------------------------------
__device__ __forceinline__ unsigned short f2bf(float f) {
    unsigned u = __float_as_uint(f);
    unsigned r = (u + 0x7fff + ((u >> 16) & 1)) >> 16;
    return (unsigned short)r;
}
__device__ __forceinline__ float bf2f(unsigned short h) {
    return __uint_as_float(((unsigned)h) << 16);
}
__device__ __forceinline__ void expand2(unsigned u, float& lo, float& hi) {
    lo = __uint_as_float(u << 16);
    hi = __uint_as_float(u & 0xffff0000u);
}
// 4 features from one uint2 (4 bf16)
__device__ __forceinline__ void accum4(float* a, uint2 g, float w) {
    float lo, hi;
    expand2(g.x, lo, hi); a[0] += lo * w; a[1] += hi * w;
    expand2(g.y, lo, hi); a[2] += lo * w; a[3] += hi * w;
}
// 2 features from one uint (2 bf16)
__device__ __forceinline__ void accum2(float* a, unsigned g, float w) {
    float lo, hi;
    expand2(g, lo, hi); a[0] += lo * w; a[1] += hi * w;
}

// async global->LDS, 16B per lane; lds dest = wave-uniform base + lane*16
__device__ __forceinline__ void gload16(const void* gp, void* lp) {
    __builtin_amdgcn_global_load_lds(
        (const __attribute__((address_space(1))) unsigned int*)gp,
        (__attribute__((address_space(3))) unsigned int*)lp,
        16, 0, 0);
}

// ---------------------------------------------------------------------------
__global__ void k_init(int* __restrict__ cnt, float* __restrict__ gb) {
    int i = blockIdx.x * blockDim.x + threadIdx.x;
    if (i < N_NODES) cnt[i] = 0;
    if (i < N_BUCKETS * 256) gb[i] = 0.0f;
}

__global__ void k_count(const int* __restrict__ col, int* __restrict__ cnt) {
    int e = blockIdx.x * blockDim.x + threadIdx.x;
    if (e < N_EDGES) atomicAdd(&cnt[col[e]], 1);
}

// --- 3-phase hierarchical exclusive scan of cnt -> off/cursor --------------
__global__ __launch_bounds__(256) void k_scanA(const int* __restrict__ cnt,
                                               int* __restrict__ bsum) {
    __shared__ int red[256];
    int t = threadIdx.x;
    int i = blockIdx.x * 256 + t;
    red[t] = (i < N_NODES) ? cnt[i] : 0;
    __syncthreads();
    for (int d = 128; d > 0; d >>= 1) {
        if (t < d) red[t] += red[t + d];
        __syncthreads();
    }
    if (t == 0) bsum[blockIdx.x] = red[0];
}

__global__ __launch_bounds__(256) void k_scanB(const int* __restrict__ bsum,
                                               int* __restrict__ bbase,
                                               int* __restrict__ off) {
    __shared__ int sc[256];
    int t = threadIdx.x;
    sc[t] = (t < SCAN_NB) ? bsum[t] : 0;
    __syncthreads();
    for (int d = 1; d < 256; d <<= 1) {
        int v = 0;
        if (t >= d) v = sc[t - d];
        __syncthreads();
        if (t >= d) sc[t] += v;
        __syncthreads();
    }
    if (t < SCAN_NB) bbase[t] = sc[t] - bsum[t];  // exclusive
    if (t == 0) off[N_NODES] = N_EDGES;
}

__global__ __launch_bounds__(256) void k_scanC(const int* __restrict__ cnt,
                                               const int* __restrict__ bbase,
                                               int* __restrict__ off,
                                               int* __restrict__ cursor,
                                               float* __restrict__ dinv) {
    __shared__ int sc[256];
    int t = threadIdx.x;
    int i = blockIdx.x * 256 + t;
    int c = (i < N_NODES) ? cnt[i] : 0;
    sc[t] = c;
    __syncthreads();
    for (int d = 1; d < 256; d <<= 1) {
        int v = 0;
        if (t >= d) v = sc[t - d];
        __syncthreads();
        if (t >= d) sc[t] += v;
        __syncthreads();
    }
    if (i < N_NODES) {
        int excl = sc[t] - c + bbase[blockIdx.x];
        off[i] = excl;
        cursor[i] = excl;
        dinv[i] = 1.0f / sqrtf((float)(c + 1));
    }
}

__global__ void k_fill(const int* __restrict__ row, const int* __restrict__ col,
                       const float* __restrict__ dinv, int* __restrict__ cursor,
                       int2* __restrict__ epack) {
    int e = blockIdx.x * blockDim.x + threadIdx.x;
    if (e >= N_EDGES) return;
    int v = col[e];
    int p = atomicAdd(&cursor[v], 1);
    int r = row[e];
    epack[p] = make_int2(r, __float_as_int(dinv[r]));
}

// W [K][N] fp32 -> transposed split bf16 WT{h,l} [N][K] (weights stay exact)
__global__ void k_prepW(const float* __restrict__ W,
                        unsigned short* __restrict__ Th,
                        unsigned short* __restrict__ Tl, int K, int N) {
    int idx = blockIdx.x * blockDim.x + threadIdx.x;
    if (idx >= K * N) return;
    int n = idx / K, k = idx - n * K;
    float v = W[(size_t)k * N + n];
    unsigned short h = f2bf(v);
    Th[idx] = h;
    Tl[idx] = f2bf(v - bf2f(h));
}

// x fp32 -> bf16 (row-major)
__global__ void k_prepX(const float* __restrict__ x, unsigned short* __restrict__ xb) {
    int i = blockIdx.x * blockDim.x + threadIdx.x;
    if (i < N_NODES * 128) xb[i] = f2bf(x[i]);
}

// ---------------------------------------------------------------------------
// Wave-per-node aggregation (R10 structure — best known; NT loads regressed):
//   res[v] = dinv[v] * ( x[v]*dinv[v] + sum_j x[r_j]*dinv[r_j] )
// One wave owns one node; each gather = one contiguous 512B/256B segment.
// POOL=0: row-major bf16 out. POOL=1: bias+relu+bucketed mean-pool.
template <int DIM, int POOL>
__global__ __launch_bounds__(256) void k_aggw(
    const unsigned short* __restrict__ xb, const int* __restrict__ off,
    const int2* __restrict__ epack, const float* __restrict__ dinv,
    const float* __restrict__ bias, unsigned short* __restrict__ outb,
    float* __restrict__ gb) {
    const int EPL = DIM / 64;     // features per lane: 4 (256) or 2 (128)
    __shared__ float gpart[256];
    if (POOL) {
        gpart[threadIdx.x] = 0.0f;
        __syncthreads();
    }
    int wv = threadIdx.x >> 6;        // wave within block
    int li = threadIdx.x & 63;        // lane
    int v = blockIdx.x * 4 + wv;      // node (grid divides N exactly)
    int f = li * EPL;
    float dv = dinv[v];
    const unsigned short* __restrict__ xf = xb + f;
    float a0[EPL], a1[EPL], a2[EPL], a3[EPL];
#pragma unroll
    for (int i = 0; i < EPL; ++i) { a0[i] = 0.f; a1[i] = 0.f; a2[i] = 0.f; a3[i] = 0.f; }
    if (EPL == 4) {
        uint2 sv = *(const uint2*)&xf[(size_t)v * DIM];
        accum4(a0, sv, dv);
    } else {
        unsigned sv = *(const unsigned*)&xf[(size_t)v * DIM];
        accum2(a0, sv, dv);
    }
    int s = off[v], e = off[v + 1];
    int j = s;
    for (; j + 4 <= e; j += 4) {
        int2 p0 = epack[j + 0];
        int2 p1 = epack[j + 1];
        int2 p2 = epack[j + 2];
        int2 p3 = epack[j + 3];
        if (EPL == 4) {
            uint2 g0 = *(const uint2*)&xf[(size_t)p0.x * DIM];
            uint2 g1 = *(const uint2*)&xf[(size_t)p1.x * DIM];
            uint2 g2 = *(const uint2*)&xf[(size_t)p2.x * DIM];
            uint2 g3 = *(const uint2*)&xf[(size_t)p3.x * DIM];
            accum4(a0, g0, __int_as_float(p0.y));
            accum4(a1, g1, __int_as_float(p1.y));
            accum4(a2, g2, __int_as_float(p2.y));
            accum4(a3, g3, __int_as_float(p3.y));
        } else {
            unsigned g0 = *(const unsigned*)&xf[(size_t)p0.x * DIM];
            unsigned g1 = *(const unsigned*)&xf[(size_t)p1.x * DIM];
            unsigned g2 = *(const unsigned*)&xf[(size_t)p2.x * DIM];
            unsigned g3 = *(const unsigned*)&xf[(size_t)p3.x * DIM];
            accum2(a0, g0, __int_as_float(p0.y));
            accum2(a1, g1, __int_as_float(p1.y));
            accum2(a2, g2, __int_as_float(p2.y));
            accum2(a3, g3, __int_as_float(p3.y));
        }
    }
    for (; j < e; ++j) {
        int2 p = epack[j];
        if (EPL == 4) {
            uint2 g = *(const uint2*)&xf[(size_t)p.x * DIM];
            accum4(a0, g, __int_as_float(p.y));
        } else {
            unsigned g = *(const unsigned*)&xf[(size_t)p.x * DIM];
            accum2(a0, g, __int_as_float(p.y));
        }
    }
    float acc[EPL];
#pragma unroll
    for (int i = 0; i < EPL; ++i)
        acc[i] = ((a0[i] + a1[i]) + (a2[i] + a3[i])) * dv;
    if (!POOL) {
        if (EPL == 4) {
            uint2 o;
            o.x = (unsigned)f2bf(acc[0]) | ((unsigned)f2bf(acc[1]) << 16);
            o.y = (unsigned)f2bf(acc[2]) | ((unsigned)f2bf(acc[3]) << 16);
            *(uint2*)&outb[(size_t)v * DIM + f] = o;
        } else {
            unsigned o = (unsigned)f2bf(acc[0]) | ((unsigned)f2bf(acc[1]) << 16);
            *(unsigned*)&outb[(size_t)v * DIM + f] = o;
        }
    } else {
#pragma unroll
        for (int i = 0; i < EPL; ++i) {
            float r = fmaxf(acc[i] + bias[f + i], 0.0f);
            atomicAdd(&gpart[f + i], r);
        }
        __syncthreads();
        atomicAdd(&gb[(blockIdx.x & (N_BUCKETS - 1)) * 256 + threadIdx.x],
                  gpart[threadIdx.x]);
    }
}

// ---------------------------------------------------------------------------
// bf16-A x split-bf16-B MFMA GEMM: C[M,N] = A[M,K] @ (Bh+Bl)[K,N] (+bias)(relu)
// B pre-transposed [N][K]. 128x128 tile, BK=32, double-buffered LDS.
// NEW: LDS-staged epilogue — quadrants dumped to the (now free) staging LDS,
// then streamed out as coalesced 16B stores (8 store instr/thread vs 64
// scalar 2B stores — the old epilogue's ~4-region scattered stores were
// estimated to cost more than the whole K-loop).
template <int BIAS, int RELU>
__global__ __launch_bounds__(256) void k_gemm_b(
    const unsigned short* __restrict__ A,
    const unsigned short* __restrict__ Bh, const unsigned short* __restrict__ Bl,
    const float* __restrict__ bias, unsigned short* __restrict__ C,
    int M, int K, int N) {
    // 48KB unified LDS: staging As/BsH/BsL during K-loop, C-tile in epilogue
    __shared__ unsigned short smem[3 * 2 * 4096];
    unsigned short* As  = smem;                 // [2][4096]
    unsigned short* BsH = smem + 2 * 4096;      // [2][4096]
    unsigned short* BsL = smem + 4 * 4096;      // [2][4096]
    int tid = threadIdx.x;
    int lane = tid & 63;
    int w = tid >> 6;
    int wr = w & 1, wc = w >> 1;
    int bm = blockIdx.x * 128, bn = blockIdx.y * 128;

    floatx4 acc[4][4];
    floatx4 zero = {0.f, 0.f, 0.f, 0.f};
#pragma unroll
    for (int t = 0; t < 4; ++t)
#pragma unroll
        for (int u = 0; u < 4; ++u) acc[t][u] = zero;

    int c0 = w * 2, c1 = c0 + 1;
    int srow = lane >> 2;
    int kg = ((lane & 3) - ((lane >> 3) & 3)) & 3;  // global k-chunk (inverse swizzle)
    int kc = kg * 8;
    const unsigned short* Ap0 = A + (size_t)(bm + c0 * 16 + srow) * K + kc;
    const unsigned short* Ap1 = A + (size_t)(bm + c1 * 16 + srow) * K + kc;
    const unsigned short* Bh0 = Bh + (size_t)(bn + c0 * 16 + srow) * K + kc;
    const unsigned short* Bh1 = Bh + (size_t)(bn + c1 * 16 + srow) * K + kc;
    const unsigned short* Bl0 = Bl + (size_t)(bn + c0 * 16 + srow) * K + kc;
    const unsigned short* Bl1 = Bl + (size_t)(bn + c1 * 16 + srow) * K + kc;

    const int KT = K >> 5;
#define STAGE(half, k0)                                       \
    do {                                                      \
        gload16(Ap0 + (k0), As + (half) * 4096 + c0 * 512);   \
        gload16(Ap1 + (k0), As + (half) * 4096 + c1 * 512);   \
        gload16(Bh0 + (k0), BsH + (half) * 4096 + c0 * 512);  \
        gload16(Bh1 + (k0), BsH + (half) * 4096 + c1 * 512);  \
        gload16(Bl0 + (k0), BsL + (half) * 4096 + c0 * 512);  \
        gload16(Bl1 + (k0), BsL + (half) * 4096 + c1 * 512);  \
    } while (0)

    STAGE(0, 0);
    __syncthreads();

    int fr = lane & 15;            // m (A) / n (B) within 16-tile
    int fq = lane >> 4;            // k-chunk 0..3
    int cl = ((fq + (fr >> 1)) & 3) * 8;  // swizzled LDS k-chunk offset

    for (int kt = 0; kt < KT; ++kt) {
        int half = kt & 1;
        if (kt + 1 < KT) STAGE(1 - half, (kt + 1) * 32);
        short8 av[4], bhv[4], blv[4];
#pragma unroll
        for (int t = 0; t < 4; ++t) {
            av[t]  = *(const short8*)&As[half * 4096 + (wr * 64 + t * 16 + fr) * 32 + cl];
            bhv[t] = *(const short8*)&BsH[half * 4096 + (wc * 64 + t * 16 + fr) * 32 + cl];
            blv[t] = *(const short8*)&BsL[half * 4096 + (wc * 64 + t * 16 + fr) * 32 + cl];
        }
#pragma unroll
        for (int t = 0; t < 4; ++t)
#pragma unroll
            for (int u = 0; u < 4; ++u) {
                acc[t][u] = __builtin_amdgcn_mfma_f32_16x16x32_bf16(av[t], bhv[u], acc[t][u], 0, 0, 0);
                acc[t][u] = __builtin_amdgcn_mfma_f32_16x16x32_bf16(av[t], blv[u], acc[t][u], 0, 0, 0);
            }
        __syncthreads();
    }
#undef STAGE

    // ---- LDS-staged epilogue ----
    // (final __syncthreads of K-loop already passed; staging LDS is free)
    // wave w dumps its 64x64 quadrant at smem + w*4096, layout row*64+col
    unsigned short* cq = smem + w * 4096;
#pragma unroll
    for (int u = 0; u < 4; ++u) {
        int colq = u * 16 + fr;   // col within quadrant
        float bv = BIAS ? bias[bn + wc * 64 + colq] : 0.0f;
#pragma unroll
        for (int t = 0; t < 4; ++t) {
#pragma unroll
            for (int r = 0; r < 4; ++r) {
                float o = acc[t][u][r] + bv;
                if (RELU) o = fmaxf(o, 0.f);
                cq[(t * 16 + fq * 4 + r) * 64 + colq] = f2bf(o);
            }
        }
    }
    __syncthreads();
    // cooperative coalesced store: 8 rounds x 16B per thread
    int lr = tid >> 4;            // 0..15: row within round
    int lc = (tid & 15) * 8;      // col base (bf16 units), 16B per thread
    int wcq = lc >> 6;            // col quadrant 0/1
    int lcq = lc & 63;
#pragma unroll
    for (int i = 0; i < 8; ++i) {
        int rowt = i * 16 + lr;   // tile row 0..127
        int wrq = rowt >> 6;
        const unsigned short* src =
            smem + (wrq + wcq * 2) * 4096 + (rowt & 63) * 64 + lcq;
        int rowg = bm + rowt;
        if (rowg < M)
            *(uint4*)&C[(size_t)rowg * N + bn + lc] = *(const uint4*)src;
    }
}

// tiny MLP; first reduces the 64 pool buckets
__global__ void k_mlp(const float* __restrict__ gb,
                      const float* __restrict__ Wf1, const float* __restrict__ bf1,
                      const float* __restrict__ Wf2, const float* __restrict__ bf2,
                      const float* __restrict__ Wf3, const float* __restrict__ bf3,
                      float* __restrict__ out) {
    __shared__ float s0[256], s1[128], s2[64];
    int t = threadIdx.x;
    float sum = 0.0f;
    for (int b = 0; b < N_BUCKETS; ++b) sum += gb[b * 256 + t];
    s0[t] = sum * (1.0f / (float)N_NODES);
    __syncthreads();
    if (t < 128) {
        float a = bf1[t];
        for (int k = 0; k < 256; ++k) a += s0[k] * Wf1[k * 128 + t];
        s1[t] = fmaxf(a, 0.0f);
    }
    __syncthreads();
    if (t < 64) {
        float a = bf2[t];
        for (int k = 0; k < 128; ++k) a += s1[k] * Wf2[k * 64 + t];
        s2[t] = fmaxf(a, 0.0f);
    }
    __syncthreads();
    if (t == 0) {
        float a = bf3[0];
        for (int k = 0; k < 64; ++k) a += s2[k] * Wf3[k];
        out[0] = a;
    }
}

extern "C" void kernel_launch(void* const* d_in, const int* in_sizes, int n_in,
                              void* d_out, int out_size, void* d_ws, size_t ws_size,
                              hipStream_t stream) {
    const float* x  = (const float*)d_in[0];
    const int* ei   = (const int*)d_in[1];
    const float* W1 = (const float*)d_in[2];
    const float* b1 = (const float*)d_in[3];
    const float* W2 = (const float*)d_in[4];
    const float* b2 = (const float*)d_in[5];
    const float* W3 = (const float*)d_in[6];
    const float* b3 = (const float*)d_in[7];
    const float* Wf1 = (const float*)d_in[8];
    const float* bf1 = (const float*)d_in[9];
    const float* Wf2 = (const float*)d_in[10];
    const float* bf2 = (const float*)d_in[11];
    const float* Wf3 = (const float*)d_in[12];
    const float* bf3 = (const float*)d_in[13];
    float* out = (float*)d_out;

    char* p = (char*)d_ws;
    auto alloc = [&](size_t bytes) {
        void* r = (void*)p;
        p += (bytes + 255) & ~((size_t)255);
        return r;
    };
    int*   cnt    = (int*)  alloc(N_NODES * sizeof(int));
    int*   off    = (int*)  alloc((N_NODES + 1) * sizeof(int));
    int*   cursor = (int*)  alloc(N_NODES * sizeof(int));
    int*   bsum   = (int*)  alloc(SCAN_NB * sizeof(int));
    int*   bbase  = (int*)  alloc(SCAN_NB * sizeof(int));
    float* dinv   = (float*)alloc(N_NODES * sizeof(float));
    int2*  epack  = (int2*) alloc((size_t)N_EDGES * sizeof(int2));
    float* gb     = (float*)alloc(N_BUCKETS * 256 * sizeof(float));
    unsigned short* W1h = (unsigned short*)alloc(128 * 256 * 2);
    unsigned short* W1l = (unsigned short*)alloc(128 * 256 * 2);
    unsigned short* W2h = (unsigned short*)alloc(256 * 512 * 2);
    unsigned short* W2l = (unsigned short*)alloc(256 * 512 * 2);
    unsigned short* W3h = (unsigned short*)alloc(512 * 256 * 2);
    unsigned short* W3l = (unsigned short*)alloc(512 * 256 * 2);
    unsigned short* xb = (unsigned short*)alloc((size_t)N_NODES * 128 * 2);
    unsigned short* t0 = (unsigned short*)alloc((size_t)M_PAD * 128 * 2);
    unsigned short* h1 = (unsigned short*)alloc((size_t)N_NODES * 256 * 2);
    unsigned short* t1 = (unsigned short*)alloc((size_t)M_PAD * 256 * 2);
    unsigned short* h2 = (unsigned short*)alloc((size_t)M_PAD * 512 * 2);
    unsigned short* t2 = (unsigned short*)alloc((size_t)N_NODES * 256 * 2);

    const int* row = ei;
    const int* col = ei + N_EDGES;

    const int NB = (N_NODES + 255) / 256;  // 196
    const int EB = (N_EDGES + 255) / 256;

    // CSR build + norm (hierarchical scan)
    k_init<<<NB, 256, 0, stream>>>(cnt, gb);
    k_count<<<EB, 256, 0, stream>>>(col, cnt);
    k_scanA<<<SCAN_NB, 256, 0, stream>>>(cnt, bsum);
    k_scanB<<<1, 256, 0, stream>>>(bsum, bbase, off);
    k_scanC<<<SCAN_NB, 256, 0, stream>>>(cnt, bbase, off, cursor, dinv);
    k_fill<<<EB, 256, 0, stream>>>(row, col, dinv, cursor, epack);

    // weight prep (transpose + exact split) and x -> bf16
    k_prepW<<<(128 * 256 + 255) / 256, 256, 0, stream>>>(W1, W1h, W1l, 128, 256);
    k_prepW<<<(256 * 512 + 255) / 256, 256, 0, stream>>>(W2, W2h, W2l, 256, 512);
    k_prepW<<<(512 * 256 + 255) / 256, 256, 0, stream>>>(W3, W3h, W3l, 512, 256);
    k_prepX<<<(N_NODES * 128 + 255) / 256, 256, 0, stream>>>(x, xb);

    const int M = N_NODES;
    const int MB = (M + 127) / 128; // 391

    // conv1: t0 = agg(xb); h1 = relu(t0@W1 + b1)
    k_aggw<128, 0><<<N_NODES / 4, 256, 0, stream>>>(
        xb, off, epack, dinv, nullptr, t0, nullptr);
    {
        dim3 grid(MB, 256 / 128);
        k_gemm_b<1, 1><<<grid, 256, 0, stream>>>(t0, W1h, W1l, b1, h1, M, 128, 256);
    }
    // conv2: t1 = agg(h1); h2 = relu(t1@W2 + b2)
    k_aggw<256, 0><<<N_NODES / 4, 256, 0, stream>>>(
        h1, off, epack, dinv, nullptr, t1, nullptr);
    {
        dim3 grid(MB, 512 / 128);
        k_gemm_b<1, 1><<<grid, 256, 0, stream>>>(t1, W2h, W2l, b2, h2, M, 256, 512);
    }
    // conv3: t2 = h2@W3; fused agg + bias + relu + bucketed mean-pool
    {
        dim3 grid(MB, 256 / 128);
        k_gemm_b<0, 0><<<grid, 256, 0, stream>>>(h2, W3h, W3l, nullptr, t2, M, 512, 256);
    }
    k_aggw<256, 1><<<N_NODES / 4, 256, 0, stream>>>(
        t2, off, epack, dinv, b3, nullptr, gb);

    // MLP (reduces buckets internally)
    k_mlp<<<1, 256, 0, stream>>>(gb, Wf1, bf1, Wf2, bf2, Wf3, bf3, out);
}

// Round 14
// 461.708 us; speedup vs baseline: 1.3285x; 1.0952x over previous
//
#include <hip/hip_runtime.h>
#include <hip/hip_bf16.h>

#define N_NODES 50000
#define N_EDGES 800000
#define N_BUCKETS 64
#define M_PAD 50048
#define SCAN_NB 196  // ceil(50000 / 256)

typedef short short8 __attribute__((ext_vector_type(8)));
typedef float floatx4 __attribute__((ext_vector_type(4)));
typedef float floatx2 __attribute__((ext_vector_type(2)));

// ---- bf16 helpers (RNE) ---------------------------------------------------
__device__ __forceinline__ unsigned short f2bf(float f) {
    unsigned u = __float_as_uint(f);
    unsigned r = (u + 0x7fff + ((u >> 16) & 1)) >> 16;
    return (unsigned short)r;
}
__device__ __forceinline__ float bf2f(unsigned short h) {
    return __uint_as_float(((unsigned)h) << 16);
}
__device__ __forceinline__ void expand2(unsigned u, float& lo, float& hi) {
    lo = __uint_as_float(u << 16);
    hi = __uint_as_float(u & 0xffff0000u);
}

// ---- fp8 e4m3 (OCP) HW conversion helpers ---------------------------------
__device__ __forceinline__ unsigned pack4_fp8(float f0, float f1, float f2, float f3) {
    int v = __builtin_amdgcn_cvt_pk_fp8_f32(f0, f1, 0, false);   // bytes 0,1
    v = __builtin_amdgcn_cvt_pk_fp8_f32(f2, f3, v, true);        // bytes 2,3
    return (unsigned)v;
}
__device__ __forceinline__ void accum_fp8x4(float* a, unsigned u, float w) {
    floatx2 lo = __builtin_amdgcn_cvt_pk_f32_fp8((int)u, false);
    floatx2 hi = __builtin_amdgcn_cvt_pk_f32_fp8((int)u, true);
    a[0] += lo[0] * w; a[1] += lo[1] * w;
    a[2] += hi[0] * w; a[3] += hi[1] * w;
}
__device__ __forceinline__ void accum_fp8x2(float* a, unsigned u, float w) {
    floatx2 lo = __builtin_amdgcn_cvt_pk_f32_fp8((int)u, false);
    a[0] += lo[0] * w; a[1] += lo[1] * w;
}

// async global->LDS, 16B per lane
__device__ __forceinline__ void gload16(const void* gp, void* lp) {
    __builtin_amdgcn_global_load_lds(
        (const __attribute__((address_space(1))) unsigned int*)gp,
        (__attribute__((address_space(3))) unsigned int*)lp,
        16, 0, 0);
}

// ---------------------------------------------------------------------------
__global__ void k_init(int* __restrict__ cnt, float* __restrict__ gb) {
    int i = blockIdx.x * blockDim.x + threadIdx.x;
    if (i < N_NODES) cnt[i] = 0;
    if (i < N_BUCKETS * 256) gb[i] = 0.0f;
}

__global__ void k_count(const int* __restrict__ col, int* __restrict__ cnt) {
    int e = blockIdx.x * blockDim.x + threadIdx.x;
    if (e < N_EDGES) atomicAdd(&cnt[col[e]], 1);
}

// --- 3-phase hierarchical exclusive scan of cnt -> off/cursor --------------
__global__ __launch_bounds__(256) void k_scanA(const int* __restrict__ cnt,
                                               int* __restrict__ bsum) {
    __shared__ int red[256];
    int t = threadIdx.x;
    int i = blockIdx.x * 256 + t;
    red[t] = (i < N_NODES) ? cnt[i] : 0;
    __syncthreads();
    for (int d = 128; d > 0; d >>= 1) {
        if (t < d) red[t] += red[t + d];
        __syncthreads();
    }
    if (t == 0) bsum[blockIdx.x] = red[0];
}

__global__ __launch_bounds__(256) void k_scanB(const int* __restrict__ bsum,
                                               int* __restrict__ bbase,
                                               int* __restrict__ off) {
    __shared__ int sc[256];
    int t = threadIdx.x;
    sc[t] = (t < SCAN_NB) ? bsum[t] : 0;
    __syncthreads();
    for (int d = 1; d < 256; d <<= 1) {
        int v = 0;
        if (t >= d) v = sc[t - d];
        __syncthreads();
        if (t >= d) sc[t] += v;
        __syncthreads();
    }
    if (t < SCAN_NB) bbase[t] = sc[t] - bsum[t];
    if (t == 0) off[N_NODES] = N_EDGES;
}

__global__ __launch_bounds__(256) void k_scanC(const int* __restrict__ cnt,
                                               const int* __restrict__ bbase,
                                               int* __restrict__ off,
                                               int* __restrict__ cursor,
                                               float* __restrict__ dinv) {
    __shared__ int sc[256];
    int t = threadIdx.x;
    int i = blockIdx.x * 256 + t;
    int c = (i < N_NODES) ? cnt[i] : 0;
    sc[t] = c;
    __syncthreads();
    for (int d = 1; d < 256; d <<= 1) {
        int v = 0;
        if (t >= d) v = sc[t - d];
        __syncthreads();
        if (t >= d) sc[t] += v;
        __syncthreads();
    }
    if (i < N_NODES) {
        int excl = sc[t] - c + bbase[blockIdx.x];
        off[i] = excl;
        cursor[i] = excl;
        dinv[i] = 1.0f / sqrtf((float)(c + 1));
    }
}

__global__ void k_fill(const int* __restrict__ row, const int* __restrict__ col,
                       const float* __restrict__ dinv, int* __restrict__ cursor,
                       int2* __restrict__ epack) {
    int e = blockIdx.x * blockDim.x + threadIdx.x;
    if (e >= N_EDGES) return;
    int v = col[e];
    int p = atomicAdd(&cursor[v], 1);
    int r = row[e];
    epack[p] = make_int2(r, __float_as_int(dinv[r]));
}

// W [K][N] fp32 -> transposed split bf16 WT{h,l} [N][K] (weights stay exact)
__global__ void k_prepW(const float* __restrict__ W,
                        unsigned short* __restrict__ Th,
                        unsigned short* __restrict__ Tl, int K, int N) {
    int idx = blockIdx.x * blockDim.x + threadIdx.x;
    if (idx >= K * N) return;
    int n = idx / K, k = idx - n * K;
    float v = W[(size_t)k * N + n];
    unsigned short h = f2bf(v);
    Th[idx] = h;
    Tl[idx] = f2bf(v - bf2f(h));
}

// x fp32 -> fp8 e4m3 (gather source for agg1); one thread per 4 features
__global__ void k_prepX8(const float* __restrict__ x, unsigned char* __restrict__ xq) {
    int i = blockIdx.x * blockDim.x + threadIdx.x;
    if (i >= N_NODES * 32) return;
    const float* s = x + (size_t)i * 4;
    *(unsigned*)&xq[(size_t)i * 4] = pack4_fp8(s[0], s[1], s[2], s[3]);
}

// ---------------------------------------------------------------------------
// Wave-per-node aggregation over fp8-e4m3 rows, fp32 accum, bf16/pool output:
//   res[v] = dinv[v] * ( x[v]*dinv[v] + sum_j x[r_j]*dinv[r_j] )
// Agg cost model (R3..R12, 7 variants): ~9.5 cyc per 64B granule per CU.
// fp8 halves row bytes: 256-dim = 256B = 4 granules/edge (vs 8 for bf16).
// POOL=0: bf16 row out (feeds GEMM). POOL=1: bias+relu+bucketed mean-pool.
template <int DIM, int POOL>
__global__ __launch_bounds__(256) void k_aggf(
    const unsigned char* __restrict__ xq, const int* __restrict__ off,
    const int2* __restrict__ epack, const float* __restrict__ dinv,
    const float* __restrict__ bias, unsigned short* __restrict__ outb,
    float* __restrict__ gb) {
    const int FPL = DIM / 64;     // features (bytes) per lane: 4 (256) or 2 (128)
    __shared__ float gpart[256];
    if (POOL) {
        gpart[threadIdx.x] = 0.0f;
        __syncthreads();
    }
    int wv = threadIdx.x >> 6;        // wave within block
    int li = threadIdx.x & 63;        // lane
    int v = blockIdx.x * 4 + wv;      // node (grid divides N exactly)
    int f = li * FPL;
    float dv = dinv[v];
    const unsigned char* __restrict__ xf = xq + f;
    float a0[FPL], a1[FPL], a2[FPL], a3[FPL];
#pragma unroll
    for (int i = 0; i < FPL; ++i) { a0[i] = 0.f; a1[i] = 0.f; a2[i] = 0.f; a3[i] = 0.f; }
    if (FPL == 4) {
        accum_fp8x4(a0, *(const unsigned*)&xf[(size_t)v * DIM], dv);
    } else {
        accum_fp8x2(a0, (unsigned)*(const unsigned short*)&xf[(size_t)v * DIM], dv);
    }
    int s = off[v], e = off[v + 1];
    int j = s;
    for (; j + 4 <= e; j += 4) {
        int2 p0 = epack[j + 0];
        int2 p1 = epack[j + 1];
        int2 p2 = epack[j + 2];
        int2 p3 = epack[j + 3];
        if (FPL == 4) {
            unsigned g0 = *(const unsigned*)&xf[(size_t)p0.x * DIM];
            unsigned g1 = *(const unsigned*)&xf[(size_t)p1.x * DIM];
            unsigned g2 = *(const unsigned*)&xf[(size_t)p2.x * DIM];
            unsigned g3 = *(const unsigned*)&xf[(size_t)p3.x * DIM];
            accum_fp8x4(a0, g0, __int_as_float(p0.y));
            accum_fp8x4(a1, g1, __int_as_float(p1.y));
            accum_fp8x4(a2, g2, __int_as_float(p2.y));
            accum_fp8x4(a3, g3, __int_as_float(p3.y));
        } else {
            unsigned g0 = *(const unsigned short*)&xf[(size_t)p0.x * DIM];
            unsigned g1 = *(const unsigned short*)&xf[(size_t)p1.x * DIM];
            unsigned g2 = *(const unsigned short*)&xf[(size_t)p2.x * DIM];
            unsigned g3 = *(const unsigned short*)&xf[(size_t)p3.x * DIM];
            accum_fp8x2(a0, g0, __int_as_float(p0.y));
            accum_fp8x2(a1, g1, __int_as_float(p1.y));
            accum_fp8x2(a2, g2, __int_as_float(p2.y));
            accum_fp8x2(a3, g3, __int_as_float(p3.y));
        }
    }
    for (; j < e; ++j) {
        int2 p = epack[j];
        if (FPL == 4) {
            accum_fp8x4(a0, *(const unsigned*)&xf[(size_t)p.x * DIM], __int_as_float(p.y));
        } else {
            accum_fp8x2(a0, (unsigned)*(const unsigned short*)&xf[(size_t)p.x * DIM],
                        __int_as_float(p.y));
        }
    }
    float acc[FPL];
#pragma unroll
    for (int i = 0; i < FPL; ++i)
        acc[i] = ((a0[i] + a1[i]) + (a2[i] + a3[i])) * dv;
    if (!POOL) {
        if (FPL == 4) {
            uint2 o;
            o.x = (unsigned)f2bf(acc[0]) | ((unsigned)f2bf(acc[1]) << 16);
            o.y = (unsigned)f2bf(acc[2]) | ((unsigned)f2bf(acc[3]) << 16);
            *(uint2*)&outb[(size_t)v * DIM + f] = o;
        } else {
            unsigned o = (unsigned)f2bf(acc[0]) | ((unsigned)f2bf(acc[1]) << 16);
            *(unsigned*)&outb[(size_t)v * DIM + f] = o;
        }
    } else {
#pragma unroll
        for (int i = 0; i < FPL; ++i) {
            float r = fmaxf(acc[i] + bias[f + i], 0.0f);
            atomicAdd(&gpart[f + i], r);
        }
        __syncthreads();
        atomicAdd(&gb[(blockIdx.x & (N_BUCKETS - 1)) * 256 + threadIdx.x],
                  gpart[threadIdx.x]);
    }
}

// ---------------------------------------------------------------------------
// bf16-A x split-bf16-B MFMA GEMM: C = A @ (Bh+Bl) (+bias)(relu)
// B pre-transposed [N][K]. 128x128 tile, BK=32, dbuf LDS, LDS-staged epilogue.
// OUTFP8=1: writeback as fp8-e4m3 (feeds the fp8 gather aggs; halves stores).
template <int BIAS, int RELU, int OUTFP8>
__global__ __launch_bounds__(256) void k_gemm_b(
    const unsigned short* __restrict__ A,
    const unsigned short* __restrict__ Bh, const unsigned short* __restrict__ Bl,
    const float* __restrict__ bias, void* __restrict__ Cout,
    int M, int K, int N) {
    __shared__ unsigned short smem[3 * 2 * 4096];
    unsigned short* As  = smem;
    unsigned short* BsH = smem + 2 * 4096;
    unsigned short* BsL = smem + 4 * 4096;
    int tid = threadIdx.x;
    int lane = tid & 63;
    int w = tid >> 6;
    int wr = w & 1, wc = w >> 1;
    int bm = blockIdx.x * 128, bn = blockIdx.y * 128;

    floatx4 acc[4][4];
    floatx4 zero = {0.f, 0.f, 0.f, 0.f};
#pragma unroll
    for (int t = 0; t < 4; ++t)
#pragma unroll
        for (int u = 0; u < 4; ++u) acc[t][u] = zero;

    int c0 = w * 2, c1 = c0 + 1;
    int srow = lane >> 2;
    int kg = ((lane & 3) - ((lane >> 3) & 3)) & 3;
    int kc = kg * 8;
    const unsigned short* Ap0 = A + (size_t)(bm + c0 * 16 + srow) * K + kc;
    const unsigned short* Ap1 = A + (size_t)(bm + c1 * 16 + srow) * K + kc;
    const unsigned short* Bh0 = Bh + (size_t)(bn + c0 * 16 + srow) * K + kc;
    const unsigned short* Bh1 = Bh + (size_t)(bn + c1 * 16 + srow) * K + kc;
    const unsigned short* Bl0 = Bl + (size_t)(bn + c0 * 16 + srow) * K + kc;
    const unsigned short* Bl1 = Bl + (size_t)(bn + c1 * 16 + srow) * K + kc;

    const int KT = K >> 5;
#define STAGE(half, k0)                                       \
    do {                                                      \
        gload16(Ap0 + (k0), As + (half) * 4096 + c0 * 512);   \
        gload16(Ap1 + (k0), As + (half) * 4096 + c1 * 512);   \
        gload16(Bh0 + (k0), BsH + (half) * 4096 + c0 * 512);  \
        gload16(Bh1 + (k0), BsH + (half) * 4096 + c1 * 512);  \
        gload16(Bl0 + (k0), BsL + (half) * 4096 + c0 * 512);  \
        gload16(Bl1 + (k0), BsL + (half) * 4096 + c1 * 512);  \
    } while (0)

    STAGE(0, 0);
    __syncthreads();

    int fr = lane & 15;
    int fq = lane >> 4;
    int cl = ((fq + (fr >> 1)) & 3) * 8;

    for (int kt = 0; kt < KT; ++kt) {
        int half = kt & 1;
        if (kt + 1 < KT) STAGE(1 - half, (kt + 1) * 32);
        short8 av[4], bhv[4], blv[4];
#pragma unroll
        for (int t = 0; t < 4; ++t) {
            av[t]  = *(const short8*)&As[half * 4096 + (wr * 64 + t * 16 + fr) * 32 + cl];
            bhv[t] = *(const short8*)&BsH[half * 4096 + (wc * 64 + t * 16 + fr) * 32 + cl];
            blv[t] = *(const short8*)&BsL[half * 4096 + (wc * 64 + t * 16 + fr) * 32 + cl];
        }
#pragma unroll
        for (int t = 0; t < 4; ++t)
#pragma unroll
            for (int u = 0; u < 4; ++u) {
                acc[t][u] = __builtin_amdgcn_mfma_f32_16x16x32_bf16(av[t], bhv[u], acc[t][u], 0, 0, 0);
                acc[t][u] = __builtin_amdgcn_mfma_f32_16x16x32_bf16(av[t], blv[u], acc[t][u], 0, 0, 0);
            }
        __syncthreads();
    }
#undef STAGE

    // ---- LDS-staged epilogue ----
    unsigned short* cq = smem + w * 4096;
#pragma unroll
    for (int u = 0; u < 4; ++u) {
        int colq = u * 16 + fr;
        float bv = BIAS ? bias[bn + wc * 64 + colq] : 0.0f;
#pragma unroll
        for (int t = 0; t < 4; ++t) {
#pragma unroll
            for (int r = 0; r < 4; ++r) {
                float o = acc[t][u][r] + bv;
                if (RELU) o = fmaxf(o, 0.f);
                cq[(t * 16 + fq * 4 + r) * 64 + colq] = f2bf(o);
            }
        }
    }
    __syncthreads();
    // cooperative coalesced store: 8 rounds x (16B bf16 | 8B fp8) per thread
    int lr = tid >> 4;
    int lc = (tid & 15) * 8;      // feature base
    int wcq = lc >> 6;
    int lcq = lc & 63;
#pragma unroll
    for (int i = 0; i < 8; ++i) {
        int rowt = i * 16 + lr;
        int wrq = rowt >> 6;
        const unsigned short* src =
            smem + (wrq + wcq * 2) * 4096 + (rowt & 63) * 64 + lcq;
        int rowg = bm + rowt;
        if (rowg < M) {
            if (!OUTFP8) {
                unsigned short* C = (unsigned short*)Cout;
                *(uint4*)&C[(size_t)rowg * N + bn + lc] = *(const uint4*)src;
            } else {
                uint4 b = *(const uint4*)src;
                float f0, f1, f2, f3, f4, f5, f6, f7;
                expand2(b.x, f0, f1); expand2(b.y, f2, f3);
                expand2(b.z, f4, f5); expand2(b.w, f6, f7);
                uint2 q;
                q.x = pack4_fp8(f0, f1, f2, f3);
                q.y = pack4_fp8(f4, f5, f6, f7);
                unsigned char* C8 = (unsigned char*)Cout;
                *(uint2*)&C8[(size_t)rowg * N + bn + lc] = q;
            }
        }
    }
}

// tiny MLP; first reduces the 64 pool buckets
__global__ void k_mlp(const float* __restrict__ gb,
                      const float* __restrict__ Wf1, const float* __restrict__ bf1,
                      const float* __restrict__ Wf2, const float* __restrict__ bf2,
                      const float* __restrict__ Wf3, const float* __restrict__ bf3,
                      float* __restrict__ out) {
    __shared__ float s0[256], s1[128], s2[64];
    int t = threadIdx.x;
    float sum = 0.0f;
    for (int b = 0; b < N_BUCKETS; ++b) sum += gb[b * 256 + t];
    s0[t] = sum * (1.0f / (float)N_NODES);
    __syncthreads();
    if (t < 128) {
        float a = bf1[t];
        for (int k = 0; k < 256; ++k) a += s0[k] * Wf1[k * 128 + t];
        s1[t] = fmaxf(a, 0.0f);
    }
    __syncthreads();
    if (t < 64) {
        float a = bf2[t];
        for (int k = 0; k < 128; ++k) a += s1[k] * Wf2[k * 64 + t];
        s2[t] = fmaxf(a, 0.0f);
    }
    __syncthreads();
    if (t == 0) {
        float a = bf3[0];
        for (int k = 0; k < 64; ++k) a += s2[k] * Wf3[k];
        out[0] = a;
    }
}

extern "C" void kernel_launch(void* const* d_in, const int* in_sizes, int n_in,
                              void* d_out, int out_size, void* d_ws, size_t ws_size,
                              hipStream_t stream) {
    const float* x  = (const float*)d_in[0];
    const int* ei   = (const int*)d_in[1];
    const float* W1 = (const float*)d_in[2];
    const float* b1 = (const float*)d_in[3];
    const float* W2 = (const float*)d_in[4];
    const float* b2 = (const float*)d_in[5];
    const float* W3 = (const float*)d_in[6];
    const float* b3 = (const float*)d_in[7];
    const float* Wf1 = (const float*)d_in[8];
    const float* bf1 = (const float*)d_in[9];
    const float* Wf2 = (const float*)d_in[10];
    const float* bf2 = (const float*)d_in[11];
    const float* Wf3 = (const float*)d_in[12];
    const float* bf3 = (const float*)d_in[13];
    float* out = (float*)d_out;

    char* p = (char*)d_ws;
    auto alloc = [&](size_t bytes) {
        void* r = (void*)p;
        p += (bytes + 255) & ~((size_t)255);
        return r;
    };
    int*   cnt    = (int*)  alloc(N_NODES * sizeof(int));
    int*   off    = (int*)  alloc((N_NODES + 1) * sizeof(int));
    int*   cursor = (int*)  alloc(N_NODES * sizeof(int));
    int*   bsum   = (int*)  alloc(SCAN_NB * sizeof(int));
    int*   bbase  = (int*)  alloc(SCAN_NB * sizeof(int));
    float* dinv   = (float*)alloc(N_NODES * sizeof(float));
    int2*  epack  = (int2*) alloc((size_t)N_EDGES * sizeof(int2));
    float* gb     = (float*)alloc(N_BUCKETS * 256 * sizeof(float));
    unsigned short* W1h = (unsigned short*)alloc(128 * 256 * 2);
    unsigned short* W1l = (unsigned short*)alloc(128 * 256 * 2);
    unsigned short* W2h = (unsigned short*)alloc(256 * 512 * 2);
    unsigned short* W2l = (unsigned short*)alloc(256 * 512 * 2);
    unsigned short* W3h = (unsigned short*)alloc(512 * 256 * 2);
    unsigned short* W3l = (unsigned short*)alloc(512 * 256 * 2);
    unsigned char*  xq  = (unsigned char*) alloc((size_t)N_NODES * 128);  // fp8
    unsigned short* t0  = (unsigned short*)alloc((size_t)M_PAD * 128 * 2);
    unsigned char*  h1q = (unsigned char*) alloc((size_t)N_NODES * 256); // fp8
    unsigned short* t1  = (unsigned short*)alloc((size_t)M_PAD * 256 * 2);
    unsigned short* h2  = (unsigned short*)alloc((size_t)M_PAD * 512 * 2);
    unsigned char*  t2q = (unsigned char*) alloc((size_t)N_NODES * 256); // fp8

    const int* row = ei;
    const int* col = ei + N_EDGES;

    const int NB = (N_NODES + 255) / 256;
    const int EB = (N_EDGES + 255) / 256;

    // CSR build + norm (hierarchical scan)
    k_init<<<NB, 256, 0, stream>>>(cnt, gb);
    k_count<<<EB, 256, 0, stream>>>(col, cnt);
    k_scanA<<<SCAN_NB, 256, 0, stream>>>(cnt, bsum);
    k_scanB<<<1, 256, 0, stream>>>(bsum, bbase, off);
    k_scanC<<<SCAN_NB, 256, 0, stream>>>(cnt, bbase, off, cursor, dinv);
    k_fill<<<EB, 256, 0, stream>>>(row, col, dinv, cursor, epack);

    // weight prep (transpose + exact split) and x -> fp8
    k_prepW<<<(128 * 256 + 255) / 256, 256, 0, stream>>>(W1, W1h, W1l, 128, 256);
    k_prepW<<<(256 * 512 + 255) / 256, 256, 0, stream>>>(W2, W2h, W2l, 256, 512);
    k_prepW<<<(512 * 256 + 255) / 256, 256, 0, stream>>>(W3, W3h, W3l, 512, 256);
    k_prepX8<<<(N_NODES * 32 + 255) / 256, 256, 0, stream>>>(x, xq);

    const int M = N_NODES;
    const int MB = (M + 127) / 128; // 391

    // conv1: t0 = agg(x_fp8) -> bf16; h1 = relu(t0@W1 + b1) -> fp8
    k_aggf<128, 0><<<N_NODES / 4, 256, 0, stream>>>(
        xq, off, epack, dinv, nullptr, t0, nullptr);
    {
        dim3 grid(MB, 256 / 128);
        k_gemm_b<1, 1, 1><<<grid, 256, 0, stream>>>(t0, W1h, W1l, b1, h1q, M, 128, 256);
    }
    // conv2: t1 = agg(h1_fp8) -> bf16; h2 = relu(t1@W2 + b2) -> bf16
    k_aggf<256, 0><<<N_NODES / 4, 256, 0, stream>>>(
        h1q, off, epack, dinv, nullptr, t1, nullptr);
    {
        dim3 grid(MB, 512 / 128);
        k_gemm_b<1, 1, 0><<<grid, 256, 0, stream>>>(t1, W2h, W2l, b2, h2, M, 256, 512);
    }
    // conv3: t2 = h2@W3 -> fp8; fused agg + bias + relu + bucketed mean-pool
    {
        dim3 grid(MB, 256 / 128);
        k_gemm_b<0, 0, 1><<<grid, 256, 0, stream>>>(h2, W3h, W3l, nullptr, t2q, M, 512, 256);
    }
    k_aggf<256, 1><<<N_NODES / 4, 256, 0, stream>>>(
        t2q, off, epack, dinv, b3, nullptr, gb);

    // MLP (reduces buckets internally)
    k_mlp<<<1, 256, 0, stream>>>(gb, Wf1, bf1, Wf2, bf2, Wf3, bf3, out);
}

// Round 15
// 459.313 us; speedup vs baseline: 1.3354x; 1.0052x over previous
//
#include <hip/hip_runtime.h>
#include <hip/hip_bf16.h>

#define N_NODES 50000
#define N_EDGES 800000
#define N_BUCKETS 64
#define M_PAD 50048
#define SCAN_NB 196  // ceil(50000 / 256)

typedef short short8 __attribute__((ext_vector_type(8)));
typedef float floatx4 __attribute__((ext_vector_type(4)));
typedef float floatx2 __attribute__((ext_vector_type(2)));

// ---- bf16 helpers (RNE) ---------------------------------------------------
__device__ __forceinline__ unsigned short f2bf(float f) {
    unsigned u = __float_as_uint(f);
    unsigned r = (u + 0x7fff + ((u >> 16) & 1)) >> 16;
    return (unsigned short)r;
}
__device__ __forceinline__ float bf2f(unsigned short h) {
    return __uint_as_float(((unsigned)h) << 16);
}
__device__ __forceinline__ void expand2(unsigned u, float& lo, float& hi) {
    lo = __uint_as_float(u << 16);
    hi = __uint_as_float(u & 0xffff0000u);
}

// ---- fp8 e4m3 (OCP) HW conversion helpers ---------------------------------
__device__ __forceinline__ unsigned pack4_fp8(float f0, float f1, float f2, float f3) {
    int v = __builtin_amdgcn_cvt_pk_fp8_f32(f0, f1, 0, false);
    v = __builtin_amdgcn_cvt_pk_fp8_f32(f2, f3, v, true);
    return (unsigned)v;
}
__device__ __forceinline__ void accum_fp8x4(float* a, unsigned u, float w) {
    floatx2 lo = __builtin_amdgcn_cvt_pk_f32_fp8((int)u, false);
    floatx2 hi = __builtin_amdgcn_cvt_pk_f32_fp8((int)u, true);
    a[0] += lo[0] * w; a[1] += lo[1] * w;
    a[2] += hi[0] * w; a[3] += hi[1] * w;
}
__device__ __forceinline__ void accum_fp8x2(float* a, unsigned u, float w) {
    floatx2 lo = __builtin_amdgcn_cvt_pk_f32_fp8((int)u, false);
    a[0] += lo[0] * w; a[1] += lo[1] * w;
}

// async global->LDS, 16B per lane
__device__ __forceinline__ void gload16(const void* gp, void* lp) {
    __builtin_amdgcn_global_load_lds(
        (const __attribute__((address_space(1))) unsigned int*)gp,
        (__attribute__((address_space(3))) unsigned int*)lp,
        16, 0, 0);
}

// ---------------------------------------------------------------------------
__global__ void k_init(int* __restrict__ cnt, float* __restrict__ gb) {
    int i = blockIdx.x * blockDim.x + threadIdx.x;
    if (i < N_NODES) cnt[i] = 0;
    if (i < N_BUCKETS * 256) gb[i] = 0.0f;
}

__global__ void k_count(const int* __restrict__ col, int* __restrict__ cnt) {
    int e = blockIdx.x * blockDim.x + threadIdx.x;
    if (e < N_EDGES) atomicAdd(&cnt[col[e]], 1);
}

// --- 3-phase hierarchical exclusive scan of PADDED capacities --------------
// cap[i] = cnt[i] rounded up to even, so every CSR segment starts 16B-aligned
// and has even length -> descriptors load as aligned int4 (2 edges/instr).
__global__ __launch_bounds__(256) void k_scanA(const int* __restrict__ cnt,
                                               int* __restrict__ bsum) {
    __shared__ int red[256];
    int t = threadIdx.x;
    int i = blockIdx.x * 256 + t;
    red[t] = (i < N_NODES) ? ((cnt[i] + 1) & ~1) : 0;
    __syncthreads();
    for (int d = 128; d > 0; d >>= 1) {
        if (t < d) red[t] += red[t + d];
        __syncthreads();
    }
    if (t == 0) bsum[blockIdx.x] = red[0];
}

__global__ __launch_bounds__(256) void k_scanB(const int* __restrict__ bsum,
                                               int* __restrict__ bbase,
                                               int* __restrict__ off) {
    __shared__ int sc[256];
    int t = threadIdx.x;
    sc[t] = (t < SCAN_NB) ? bsum[t] : 0;
    __syncthreads();
    for (int d = 1; d < 256; d <<= 1) {
        int v = 0;
        if (t >= d) v = sc[t - d];
        __syncthreads();
        if (t >= d) sc[t] += v;
        __syncthreads();
    }
    if (t < SCAN_NB) bbase[t] = sc[t] - bsum[t];
    if (t == SCAN_NB - 1) off[N_NODES] = sc[t];   // padded total
}

__global__ __launch_bounds__(256) void k_scanC(const int* __restrict__ cnt,
                                               const int* __restrict__ bbase,
                                               int* __restrict__ off,
                                               int* __restrict__ cursor,
                                               float* __restrict__ dinv,
                                               int2* __restrict__ epack) {
    __shared__ int sc[256];
    int t = threadIdx.x;
    int i = blockIdx.x * 256 + t;
    int c = (i < N_NODES) ? cnt[i] : 0;
    int cap = (c + 1) & ~1;
    sc[t] = cap;
    __syncthreads();
    for (int d = 1; d < 256; d <<= 1) {
        int v = 0;
        if (t >= d) v = sc[t - d];
        __syncthreads();
        if (t >= d) sc[t] += v;
        __syncthreads();
    }
    if (i < N_NODES) {
        int excl = sc[t] - cap + bbase[blockIdx.x];
        off[i] = excl;
        cursor[i] = excl;
        dinv[i] = 1.0f / sqrtf((float)(c + 1));
        if (c & 1) epack[excl + c] = make_int2(i, 0);  // dummy pad edge, w=0
    }
}

__global__ void k_fill(const int* __restrict__ row, const int* __restrict__ col,
                       const float* __restrict__ dinv, int* __restrict__ cursor,
                       int2* __restrict__ epack) {
    int e = blockIdx.x * blockDim.x + threadIdx.x;
    if (e >= N_EDGES) return;
    int v = col[e];
    int p = atomicAdd(&cursor[v], 1);
    int r = row[e];
    epack[p] = make_int2(r, __float_as_int(dinv[r]));
}

// W [K][N] fp32 -> transposed split bf16 WT{h,l} [N][K] (weights stay exact)
__global__ void k_prepW(const float* __restrict__ W,
                        unsigned short* __restrict__ Th,
                        unsigned short* __restrict__ Tl, int K, int N) {
    int idx = blockIdx.x * blockDim.x + threadIdx.x;
    if (idx >= K * N) return;
    int n = idx / K, k = idx - n * K;
    float v = W[(size_t)k * N + n];
    unsigned short h = f2bf(v);
    Th[idx] = h;
    Tl[idx] = f2bf(v - bf2f(h));
}

// x fp32 -> fp8 e4m3; one thread per 4 features
__global__ void k_prepX8(const float* __restrict__ x, unsigned char* __restrict__ xq) {
    int i = blockIdx.x * blockDim.x + threadIdx.x;
    if (i >= N_NODES * 32) return;
    const float* s = x + (size_t)i * 4;
    *(unsigned*)&xq[(size_t)i * 4] = pack4_fp8(s[0], s[1], s[2], s[3]);
}

// ---------------------------------------------------------------------------
// Wave-per-node aggregation over fp8-e4m3 rows, fp32 accum.
// CSR segments are even-length (padded) -> descriptors load as aligned int4
// (2 edges per instruction, halving descriptor instruction count).
// POOL=0: bf16 row out (feeds GEMM). POOL=1: bias+relu+bucketed mean-pool.
template <int DIM, int POOL>
__global__ __launch_bounds__(256) void k_aggf(
    const unsigned char* __restrict__ xq, const int* __restrict__ off,
    const int2* __restrict__ epack, const float* __restrict__ dinv,
    const float* __restrict__ bias, unsigned short* __restrict__ outb,
    float* __restrict__ gb) {
    const int FPL = DIM / 64;     // features (bytes) per lane: 4 (256) or 2 (128)
    __shared__ float gpart[256];
    if (POOL) {
        gpart[threadIdx.x] = 0.0f;
        __syncthreads();
    }
    int wv = threadIdx.x >> 6;
    int li = threadIdx.x & 63;
    int v = blockIdx.x * 4 + wv;      // grid divides N exactly
    int f = li * FPL;
    float dv = dinv[v];
    const unsigned char* __restrict__ xf = xq + f;
    float a0[FPL], a1[FPL], a2[FPL], a3[FPL];
#pragma unroll
    for (int i = 0; i < FPL; ++i) { a0[i] = 0.f; a1[i] = 0.f; a2[i] = 0.f; a3[i] = 0.f; }
    if (FPL == 4) {
        accum_fp8x4(a0, *(const unsigned*)&xf[(size_t)v * DIM], dv);
    } else {
        accum_fp8x2(a0, (unsigned)*(const unsigned short*)&xf[(size_t)v * DIM], dv);
    }
    int s = off[v], e = off[v + 1];   // even-aligned, even length
    int j = s;
    for (; j + 4 <= e; j += 4) {
        int4 d0 = *(const int4*)&epack[j];       // edges j, j+1
        int4 d1 = *(const int4*)&epack[j + 2];   // edges j+2, j+3
        if (FPL == 4) {
            unsigned g0 = *(const unsigned*)&xf[(size_t)d0.x * DIM];
            unsigned g1 = *(const unsigned*)&xf[(size_t)d0.z * DIM];
            unsigned g2 = *(const unsigned*)&xf[(size_t)d1.x * DIM];
            unsigned g3 = *(const unsigned*)&xf[(size_t)d1.z * DIM];
            accum_fp8x4(a0, g0, __int_as_float(d0.y));
            accum_fp8x4(a1, g1, __int_as_float(d0.w));
            accum_fp8x4(a2, g2, __int_as_float(d1.y));
            accum_fp8x4(a3, g3, __int_as_float(d1.w));
        } else {
            unsigned g0 = *(const unsigned short*)&xf[(size_t)d0.x * DIM];
            unsigned g1 = *(const unsigned short*)&xf[(size_t)d0.z * DIM];
            unsigned g2 = *(const unsigned short*)&xf[(size_t)d1.x * DIM];
            unsigned g3 = *(const unsigned short*)&xf[(size_t)d1.z * DIM];
            accum_fp8x2(a0, g0, __int_as_float(d0.y));
            accum_fp8x2(a1, g1, __int_as_float(d0.w));
            accum_fp8x2(a2, g2, __int_as_float(d1.y));
            accum_fp8x2(a3, g3, __int_as_float(d1.w));
        }
    }
    if (j < e) {  // exactly 2 edges left (even padding)
        int4 d0 = *(const int4*)&epack[j];
        if (FPL == 4) {
            unsigned g0 = *(const unsigned*)&xf[(size_t)d0.x * DIM];
            unsigned g1 = *(const unsigned*)&xf[(size_t)d0.z * DIM];
            accum_fp8x4(a0, g0, __int_as_float(d0.y));
            accum_fp8x4(a1, g1, __int_as_float(d0.w));
        } else {
            unsigned g0 = *(const unsigned short*)&xf[(size_t)d0.x * DIM];
            unsigned g1 = *(const unsigned short*)&xf[(size_t)d0.z * DIM];
            accum_fp8x2(a0, g0, __int_as_float(d0.y));
            accum_fp8x2(a1, g1, __int_as_float(d0.w));
        }
    }
    float acc[FPL];
#pragma unroll
    for (int i = 0; i < FPL; ++i)
        acc[i] = ((a0[i] + a1[i]) + (a2[i] + a3[i])) * dv;
    if (!POOL) {
        if (FPL == 4) {
            uint2 o;
            o.x = (unsigned)f2bf(acc[0]) | ((unsigned)f2bf(acc[1]) << 16);
            o.y = (unsigned)f2bf(acc[2]) | ((unsigned)f2bf(acc[3]) << 16);
            *(uint2*)&outb[(size_t)v * DIM + f] = o;
        } else {
            unsigned o = (unsigned)f2bf(acc[0]) | ((unsigned)f2bf(acc[1]) << 16);
            *(unsigned*)&outb[(size_t)v * DIM + f] = o;
        }
    } else {
#pragma unroll
        for (int i = 0; i < FPL; ++i) {
            float r = fmaxf(acc[i] + bias[f + i], 0.0f);
            atomicAdd(&gpart[f + i], r);
        }
        __syncthreads();
        atomicAdd(&gb[(blockIdx.x & (N_BUCKETS - 1)) * 256 + threadIdx.x],
                  gpart[threadIdx.x]);
    }
}

// ---------------------------------------------------------------------------
// bf16-A x split-bf16-B MFMA GEMM: C = A @ (Bh+Bl) (+bias)(relu)
// B pre-transposed [N][K]. 128x128 tile, BK=32, SINGLE-buffered LDS (32KB ->
// 5 blocks/CU; explicit dbuf was occupancy-limited at 48KB and cross-block
// implicit overlap is the better latency-hiding mechanism). LDS-staged
// coalesced epilogue (reuses all 32KB). OUTFP8=1: fp8-e4m3 writeback.
template <int BIAS, int RELU, int OUTFP8>
__global__ __launch_bounds__(256) void k_gemm_b(
    const unsigned short* __restrict__ A,
    const unsigned short* __restrict__ Bh, const unsigned short* __restrict__ Bl,
    const float* __restrict__ bias, void* __restrict__ Cout,
    int M, int K, int N) {
    __shared__ unsigned short smem[4 * 4096];   // 32KB
    unsigned short* As  = smem;                 // 8KB
    unsigned short* BsH = smem + 4096;          // 8KB
    unsigned short* BsL = smem + 8192;          // 8KB
    int tid = threadIdx.x;
    int lane = tid & 63;
    int w = tid >> 6;
    int wr = w & 1, wc = w >> 1;
    int bm = blockIdx.x * 128, bn = blockIdx.y * 128;

    floatx4 acc[4][4];
    floatx4 zero = {0.f, 0.f, 0.f, 0.f};
#pragma unroll
    for (int t = 0; t < 4; ++t)
#pragma unroll
        for (int u = 0; u < 4; ++u) acc[t][u] = zero;

    int c0 = w * 2, c1 = c0 + 1;
    int srow = lane >> 2;
    int kg = ((lane & 3) - ((lane >> 3) & 3)) & 3;
    int kc = kg * 8;
    const unsigned short* Ap0 = A + (size_t)(bm + c0 * 16 + srow) * K + kc;
    const unsigned short* Ap1 = A + (size_t)(bm + c1 * 16 + srow) * K + kc;
    const unsigned short* Bh0 = Bh + (size_t)(bn + c0 * 16 + srow) * K + kc;
    const unsigned short* Bh1 = Bh + (size_t)(bn + c1 * 16 + srow) * K + kc;
    const unsigned short* Bl0 = Bl + (size_t)(bn + c0 * 16 + srow) * K + kc;
    const unsigned short* Bl1 = Bl + (size_t)(bn + c1 * 16 + srow) * K + kc;

    const int KT = K >> 5;
    int fr = lane & 15;
    int fq = lane >> 4;
    int cl = ((fq + (fr >> 1)) & 3) * 8;

    for (int kt = 0; kt < KT; ++kt) {
        int k0 = kt * 32;
        gload16(Ap0 + k0, As + c0 * 512);
        gload16(Ap1 + k0, As + c1 * 512);
        gload16(Bh0 + k0, BsH + c0 * 512);
        gload16(Bh1 + k0, BsH + c1 * 512);
        gload16(Bl0 + k0, BsL + c0 * 512);
        gload16(Bl1 + k0, BsL + c1 * 512);
        __syncthreads();
        short8 av[4], bhv[4], blv[4];
#pragma unroll
        for (int t = 0; t < 4; ++t) {
            av[t]  = *(const short8*)&As[(wr * 64 + t * 16 + fr) * 32 + cl];
            bhv[t] = *(const short8*)&BsH[(wc * 64 + t * 16 + fr) * 32 + cl];
            blv[t] = *(const short8*)&BsL[(wc * 64 + t * 16 + fr) * 32 + cl];
        }
#pragma unroll
        for (int t = 0; t < 4; ++t)
#pragma unroll
            for (int u = 0; u < 4; ++u) {
                acc[t][u] = __builtin_amdgcn_mfma_f32_16x16x32_bf16(av[t], bhv[u], acc[t][u], 0, 0, 0);
                acc[t][u] = __builtin_amdgcn_mfma_f32_16x16x32_bf16(av[t], blv[u], acc[t][u], 0, 0, 0);
            }
        __syncthreads();
    }

    // ---- LDS-staged epilogue (reuses all 32KB) ----
    unsigned short* cq = smem + w * 4096;
#pragma unroll
    for (int u = 0; u < 4; ++u) {
        int colq = u * 16 + fr;
        float bv = BIAS ? bias[bn + wc * 64 + colq] : 0.0f;
#pragma unroll
        for (int t = 0; t < 4; ++t) {
#pragma unroll
            for (int r = 0; r < 4; ++r) {
                float o = acc[t][u][r] + bv;
                if (RELU) o = fmaxf(o, 0.f);
                cq[(t * 16 + fq * 4 + r) * 64 + colq] = f2bf(o);
            }
        }
    }
    __syncthreads();
    int lr = tid >> 4;
    int lc = (tid & 15) * 8;
    int wcq = lc >> 6;
    int lcq = lc & 63;
#pragma unroll
    for (int i = 0; i < 8; ++i) {
        int rowt = i * 16 + lr;
        int wrq = rowt >> 6;
        const unsigned short* src =
            smem + (wrq + wcq * 2) * 4096 + (rowt & 63) * 64 + lcq;
        int rowg = bm + rowt;
        if (rowg < M) {
            if (!OUTFP8) {
                unsigned short* C = (unsigned short*)Cout;
                *(uint4*)&C[(size_t)rowg * N + bn + lc] = *(const uint4*)src;
            } else {
                uint4 b = *(const uint4*)src;
                float f0, f1, f2, f3, f4, f5, f6, f7;
                expand2(b.x, f0, f1); expand2(b.y, f2, f3);
                expand2(b.z, f4, f5); expand2(b.w, f6, f7);
                uint2 q;
                q.x = pack4_fp8(f0, f1, f2, f3);
                q.y = pack4_fp8(f4, f5, f6, f7);
                unsigned char* C8 = (unsigned char*)Cout;
                *(uint2*)&C8[(size_t)rowg * N + bn + lc] = q;
            }
        }
    }
}

// tiny MLP; first reduces the 64 pool buckets
__global__ void k_mlp(const float* __restrict__ gb,
                      const float* __restrict__ Wf1, const float* __restrict__ bf1,
                      const float* __restrict__ Wf2, const float* __restrict__ bf2,
                      const float* __restrict__ Wf3, const float* __restrict__ bf3,
                      float* __restrict__ out) {
    __shared__ float s0[256], s1[128], s2[64];
    int t = threadIdx.x;
    float sum = 0.0f;
    for (int b = 0; b < N_BUCKETS; ++b) sum += gb[b * 256 + t];
    s0[t] = sum * (1.0f / (float)N_NODES);
    __syncthreads();
    if (t < 128) {
        float a = bf1[t];
        for (int k = 0; k < 256; ++k) a += s0[k] * Wf1[k * 128 + t];
        s1[t] = fmaxf(a, 0.0f);
    }
    __syncthreads();
    if (t < 64) {
        float a = bf2[t];
        for (int k = 0; k < 128; ++k) a += s1[k] * Wf2[k * 64 + t];
        s2[t] = fmaxf(a, 0.0f);
    }
    __syncthreads();
    if (t == 0) {
        float a = bf3[0];
        for (int k = 0; k < 64; ++k) a += s2[k] * Wf3[k];
        out[0] = a;
    }
}

extern "C" void kernel_launch(void* const* d_in, const int* in_sizes, int n_in,
                              void* d_out, int out_size, void* d_ws, size_t ws_size,
                              hipStream_t stream) {
    const float* x  = (const float*)d_in[0];
    const int* ei   = (const int*)d_in[1];
    const float* W1 = (const float*)d_in[2];
    const float* b1 = (const float*)d_in[3];
    const float* W2 = (const float*)d_in[4];
    const float* b2 = (const float*)d_in[5];
    const float* W3 = (const float*)d_in[6];
    const float* b3 = (const float*)d_in[7];
    const float* Wf1 = (const float*)d_in[8];
    const float* bf1 = (const float*)d_in[9];
    const float* Wf2 = (const float*)d_in[10];
    const float* bf2 = (const float*)d_in[11];
    const float* Wf3 = (const float*)d_in[12];
    const float* bf3 = (const float*)d_in[13];
    float* out = (float*)d_out;

    char* p = (char*)d_ws;
    auto alloc = [&](size_t bytes) {
        void* r = (void*)p;
        p += (bytes + 255) & ~((size_t)255);
        return r;
    };
    int*   cnt    = (int*)  alloc(N_NODES * sizeof(int));
    int*   off    = (int*)  alloc((N_NODES + 1) * sizeof(int));
    int*   cursor = (int*)  alloc(N_NODES * sizeof(int));
    int*   bsum   = (int*)  alloc(SCAN_NB * sizeof(int));
    int*   bbase  = (int*)  alloc(SCAN_NB * sizeof(int));
    float* dinv   = (float*)alloc(N_NODES * sizeof(float));
    int2*  epack  = (int2*) alloc((size_t)(N_EDGES + N_NODES) * sizeof(int2)); // + pad slots
    float* gb     = (float*)alloc(N_BUCKETS * 256 * sizeof(float));
    unsigned short* W1h = (unsigned short*)alloc(128 * 256 * 2);
    unsigned short* W1l = (unsigned short*)alloc(128 * 256 * 2);
    unsigned short* W2h = (unsigned short*)alloc(256 * 512 * 2);
    unsigned short* W2l = (unsigned short*)alloc(256 * 512 * 2);
    unsigned short* W3h = (unsigned short*)alloc(512 * 256 * 2);
    unsigned short* W3l = (unsigned short*)alloc(512 * 256 * 2);
    unsigned char*  xq  = (unsigned char*) alloc((size_t)N_NODES * 128);
    unsigned short* t0  = (unsigned short*)alloc((size_t)M_PAD * 128 * 2);
    unsigned char*  h1q = (unsigned char*) alloc((size_t)N_NODES * 256);
    unsigned short* t1  = (unsigned short*)alloc((size_t)M_PAD * 256 * 2);
    unsigned short* h2  = (unsigned short*)alloc((size_t)M_PAD * 512 * 2);
    unsigned char*  t2q = (unsigned char*) alloc((size_t)N_NODES * 256);

    const int* row = ei;
    const int* col = ei + N_EDGES;

    const int NB = (N_NODES + 255) / 256;
    const int EB = (N_EDGES + 255) / 256;

    // CSR build + norm (hierarchical scan over even-padded capacities)
    k_init<<<NB, 256, 0, stream>>>(cnt, gb);
    k_count<<<EB, 256, 0, stream>>>(col, cnt);
    k_scanA<<<SCAN_NB, 256, 0, stream>>>(cnt, bsum);
    k_scanB<<<1, 256, 0, stream>>>(bsum, bbase, off);
    k_scanC<<<SCAN_NB, 256, 0, stream>>>(cnt, bbase, off, cursor, dinv, epack);
    k_fill<<<EB, 256, 0, stream>>>(row, col, dinv, cursor, epack);

    // weight prep (transpose + exact split) and x -> fp8
    k_prepW<<<(128 * 256 + 255) / 256, 256, 0, stream>>>(W1, W1h, W1l, 128, 256);
    k_prepW<<<(256 * 512 + 255) / 256, 256, 0, stream>>>(W2, W2h, W2l, 256, 512);
    k_prepW<<<(512 * 256 + 255) / 256, 256, 0, stream>>>(W3, W3h, W3l, 512, 256);
    k_prepX8<<<(N_NODES * 32 + 255) / 256, 256, 0, stream>>>(x, xq);

    const int M = N_NODES;
    const int MB = (M + 127) / 128; // 391

    // conv1: t0 = agg(x_fp8) -> bf16; h1 = relu(t0@W1 + b1) -> fp8
    k_aggf<128, 0><<<N_NODES / 4, 256, 0, stream>>>(
        xq, off, epack, dinv, nullptr, t0, nullptr);
    {
        dim3 grid(MB, 256 / 128);
        k_gemm_b<1, 1, 1><<<grid, 256, 0, stream>>>(t0, W1h, W1l, b1, h1q, M, 128, 256);
    }
    // conv2: t1 = agg(h1_fp8) -> bf16; h2 = relu(t1@W2 + b2) -> bf16
    k_aggf<256, 0><<<N_NODES / 4, 256, 0, stream>>>(
        h1q, off, epack, dinv, nullptr, t1, nullptr);
    {
        dim3 grid(MB, 512 / 128);
        k_gemm_b<1, 1, 0><<<grid, 256, 0, stream>>>(t1, W2h, W2l, b2, h2, M, 256, 512);
    }
    // conv3: t2 = h2@W3 -> fp8; fused agg + bias + relu + bucketed mean-pool
    {
        dim3 grid(MB, 256 / 128);
        k_gemm_b<0, 0, 1><<<grid, 256, 0, stream>>>(h2, W3h, W3l, nullptr, t2q, M, 512, 256);
    }
    k_aggf<256, 1><<<N_NODES / 4, 256, 0, stream>>>(
        t2q, off, epack, dinv, b3, nullptr, gb);

    // MLP (reduces buckets internally)
    k_mlp<<<1, 256, 0, stream>>>(gb, Wf1, bf1, Wf2, bf2, Wf3, bf3, out);
}